// Round 3
// baseline (12894.339 us; speedup 1.0000x reference)
//
#include <hip/hip_runtime.h>
#include <hip/hip_bf16.h>
#include <stdint.h>

#define EPS_GN 1e-5f
#define NEG_SLOPE 0.2f

static constexpr int  Bn   = 2;
static constexpr int  Cn   = 32;
static constexpr int  Dn   = 24;
static constexpr int  Hn   = 160;
static constexpr int  Wn   = 160;
static constexpr int  HWn  = Hn * Wn;              // 25600
static constexpr long DHWn = (long)Dn * HWn;       // 614400
static constexpr long NPIX = (long)Bn * Dn * HWn;  // 1228800
static constexpr int  NBLK = 800;                  // persistent GRU grid

using frag8  = __attribute__((ext_vector_type(8)))  short;  // 8 bf16 (4 VGPRs)
using accf16 = __attribute__((ext_vector_type(16))) float;  // 32x32 C/D frag

__device__ __forceinline__ float bf2f(__hip_bfloat16 v) { return __bfloat162float(v); }
__device__ __forceinline__ __hip_bfloat16 f2bf(float v) { return __float2bfloat16(v); }
__device__ __forceinline__ float sigm(float v) { return 1.f / (1.f + __expf(-v)); }
__device__ __forceinline__ float tanh_(float v) {
    float e = __expf(2.f * v);
    return 1.f - 2.f / (e + 1.f);
}

// ---------------------------------------------------------------------------
// Grid-wide barrier (all NBLK blocks co-resident). bar[0]=arrival, bar[1]=phase.
// Device-scope atomics + __threadfence (wb/inv of non-coherent XCD L2s).
// ---------------------------------------------------------------------------
__device__ __forceinline__ void grid_barrier(int* bar, int ph) {
    __syncthreads();
    if (threadIdx.x == 0) {
        __threadfence();
        int n = __hip_atomic_fetch_add(&bar[0], 1, __ATOMIC_ACQ_REL, __HIP_MEMORY_SCOPE_AGENT);
        if (n == NBLK - 1) {
            __hip_atomic_store(&bar[0], 0, __ATOMIC_RELAXED, __HIP_MEMORY_SCOPE_AGENT);
            __hip_atomic_store(&bar[1], ph, __ATOMIC_RELEASE, __HIP_MEMORY_SCOPE_AGENT);
        } else {
            while (__hip_atomic_load(&bar[1], __ATOMIC_ACQUIRE, __HIP_MEMORY_SCOPE_AGENT) < ph)
                __builtin_amdgcn_s_sleep(2);
        }
        __threadfence();
    }
    __syncthreads();
}

// ---------------------------------------------------------------------------
// Pack conv1 weight w_f1 [64][32][3] into MFMA B-frag order.
// ---------------------------------------------------------------------------
__global__ __launch_bounds__(256) void bpack1_kernel(
    const float* __restrict__ w, __hip_bfloat16* __restrict__ dst)
{
    int t = blockIdx.x * 256 + threadIdx.x;
    if (t >= 6 * 2 * 64 * 8) return;
    int j    = t & 7;
    int lane = (t >> 3) & 63;
    int idx  = t >> 9;           // kb*2+nt
    int nt   = idx & 1;
    int kb   = idx >> 1;         // 0..5
    int o    = nt * 32 + (lane & 31);
    int k    = kb * 16 + (lane >> 5) * 8 + j;
    int ci   = k & 31;
    int kd   = k >> 5;
    dst[t] = f2bf(w[(o * 32 + ci) * 3 + kd]);
}

// ---------------------------------------------------------------------------
// Pack conv2 weight w_f2 [32][64][3]. K-order: k = kd*64 + ci.
// ---------------------------------------------------------------------------
__global__ __launch_bounds__(256) void bpack2_kernel(
    const float* __restrict__ w, __hip_bfloat16* __restrict__ dst)
{
    int t = blockIdx.x * 256 + threadIdx.x;
    if (t >= 12 * 64 * 8) return;
    int j    = t & 7;
    int lane = (t >> 3) & 63;
    int kb   = t >> 9;           // 0..11
    int o    = lane & 31;
    int k    = kb * 16 + (lane >> 5) * 8 + j;
    int ci   = k & 63;
    int kd   = k >> 6;
    dst[t] = f2bf(w[(o * 64 + ci) * 3 + kd]);
}

// ---------------------------------------------------------------------------
// Pack GRU conv weight [32][64][3][3] fp32 into MFMA B-fragment lane order.
// ---------------------------------------------------------------------------
__global__ __launch_bounds__(256) void bpack_kernel(
    const float* __restrict__ w, __hip_bfloat16* __restrict__ dst)
{
    int t = blockIdx.x * 256 + threadIdx.x;
    if (t >= 9 * 4 * 64 * 8) return;
    int j    = t & 7;
    int lane = (t >> 3) & 63;
    int kb   = (t >> 9) & 3;
    int tap  = t >> 11;
    int ci   = kb * 16 + (lane >> 5) * 8 + j;
    int o    = lane & 31;
    dst[t] = f2bf(w[(o * 64 + ci) * 9 + tap]);
}

// ---------------------------------------------------------------------------
// x [B][C][D][HW] fp32 -> xhwc [B][D][HW][32] bf16 via LDS transpose tile.
// ---------------------------------------------------------------------------
__global__ __launch_bounds__(256) void tohwc_kernel(
    const float* __restrict__ x, __hip_bfloat16* __restrict__ xhwc)
{
    __shared__ float tile[32][65];
    int bd = blockIdx.y;            // b*Dn+d
    int b  = bd / Dn, d = bd % Dn;
    int p0 = blockIdx.x * 64;
    const float* xb = x + (long)b * Cn * DHWn + (long)d * HWn + p0;
    for (int e = threadIdx.x; e < 2048; e += 256) {
        int c = e >> 6, p = e & 63;
        tile[c][p] = xb[(long)c * DHWn + p];
    }
    __syncthreads();
    __hip_bfloat16* ob = xhwc + ((long)bd * HWn + p0) * 32;
    for (int e = threadIdx.x; e < 2048; e += 256) {
        int p = e >> 5, c = e & 31;
        ob[p * 32 + c] = f2bf(tile[c][p]);
    }
}

// ---------------------------------------------------------------------------
// conv1 via MFMA: M=pixels (32/tile), N=64, K=96. GN stats fused.
// XCD-chunked block swizzle (2400 = 8 x 300) for d-slice L2 locality.
// ---------------------------------------------------------------------------
__global__ __launch_bounds__(256) void conv1_mfma(
    const __hip_bfloat16* __restrict__ xhwc,
    const __hip_bfloat16* __restrict__ Bp1,
    const float* __restrict__ b1,
    int b,
    __hip_bfloat16* __restrict__ A,
    float* __restrict__ gsum, float* __restrict__ gsq)
{
    int wave = threadIdx.x >> 6;
    int lane = threadIdx.x & 63;
    int ml   = lane & 31;
    int kh   = lane >> 5;
    int bid  = blockIdx.x;
    int sw   = (bid & 7) * 300 + (bid >> 3);
    int tile0 = sw * 8 + wave * 2;   // even; 800 tiles per d-slice

    frag8 bf[6][2];
#pragma unroll
    for (int kb = 0; kb < 6; kb++)
#pragma unroll
        for (int nt = 0; nt < 2; nt++)
            bf[kb][nt] = *(const frag8*)(Bp1 + ((kb * 2 + nt) * 64 + lane) * 8);

    int d  = tile0 / 800;
    int p0 = (tile0 % 800) * 32;

    accf16 acc[2][2];
#pragma unroll
    for (int t = 0; t < 2; t++)
#pragma unroll
        for (int nt = 0; nt < 2; nt++)
#pragma unroll
            for (int i = 0; i < 16; i++) acc[t][nt][i] = 0.f;

    for (int kd = 0; kd < 3; kd++) {
        int dd = d + kd - 1;
        bool valid = (unsigned)dd < (unsigned)Dn;
        const __hip_bfloat16* rp = xhwc + ((long)(b * Dn + dd) * HWn) * 32;
#pragma unroll
        for (int h2 = 0; h2 < 2; h2++) {
            int kb = kd * 2 + h2;
#pragma unroll
            for (int t = 0; t < 2; t++) {
                frag8 a = {};
                if (valid)
                    a = *(const frag8*)(rp + (long)(p0 + t * 32 + ml) * 32 + h2 * 16 + kh * 8);
                acc[t][0] = __builtin_amdgcn_mfma_f32_32x32x16_bf16(a, bf[kb][0], acc[t][0], 0, 0, 0);
                acc[t][1] = __builtin_amdgcn_mfma_f32_32x32x16_bf16(a, bf[kb][1], acc[t][1], 0, 0, 0);
            }
        }
    }

    float bias[2] = { b1[ml], b1[32 + ml] };
    float s[2] = {0.f, 0.f}, q[2] = {0.f, 0.f};
    __hip_bfloat16* Ap = A + (long)d * HWn * 64;
#pragma unroll
    for (int t = 0; t < 2; t++) {
        int pb = p0 + t * 32;
#pragma unroll
        for (int nt = 0; nt < 2; nt++) {
#pragma unroll
            for (int i = 0; i < 16; i++) {
                int row = (i & 3) + 8 * (i >> 2) + 4 * kh;
                float v = acc[t][nt][i] + bias[nt];
                Ap[(long)(pb + row) * 64 + nt * 32 + ml] = f2bf(v);
                s[nt] += v;
                q[nt] += v * v;
            }
        }
    }
#pragma unroll
    for (int nt = 0; nt < 2; nt++) {
        s[nt] += __shfl_xor(s[nt], 32);
        q[nt] += __shfl_xor(q[nt], 32);
    }
    __shared__ float ss[64], sq[64];
    if (threadIdx.x < 64) { ss[threadIdx.x] = 0.f; sq[threadIdx.x] = 0.f; }
    __syncthreads();
    if (lane < 32) {
        atomicAdd(&ss[ml],      s[0]); atomicAdd(&sq[ml],      q[0]);
        atomicAdd(&ss[32 + ml], s[1]); atomicAdd(&sq[32 + ml], q[1]);
    }
    __syncthreads();
    if (threadIdx.x < 64) {
        atomicAdd(&gsum[b * 64 + threadIdx.x], ss[threadIdx.x]);
        atomicAdd(&gsq [b * 64 + threadIdx.x], sq[threadIdx.x]);
    }
}

__global__ __launch_bounds__(64) void finalize_kernel(
    const float* __restrict__ gsum, const float* __restrict__ gsq,
    const float* __restrict__ gn_g, const float* __restrict__ gn_b,
    float* __restrict__ scal, float* __restrict__ shft, int b)
{
    int ci = threadIdx.x;
    if (ci >= 64) return;
    int g = ci >> 3;
    float s = 0.f, qq = 0.f;
#pragma unroll
    for (int k = 0; k < 8; k++) {
        s  += gsum[b * 64 + g * 8 + k];
        qq += gsq [b * 64 + g * 8 + k];
    }
    float N   = 8.0f * (float)DHWn;
    float mu  = s / N;
    float var = qq / N - mu * mu;
    float rs  = rsqrtf(var + EPS_GN);
    float scv = rs * gn_g[ci];
    scal[b * 64 + ci] = scv;
    shft[b * 64 + ci] = gn_b[ci] - mu * scv;
}

// ---------------------------------------------------------------------------
// In-place GN affine + LeakyReLU on A [D][HW][64] bf16 (one batch).
// ---------------------------------------------------------------------------
__global__ __launch_bounds__(256) void act_kernel(
    __hip_bfloat16* __restrict__ A,
    const float* __restrict__ scal, const float* __restrict__ shft, int b)
{
    __shared__ float sc[64], sh[64];
    if (threadIdx.x < 64) {
        sc[threadIdx.x] = scal[b * 64 + threadIdx.x];
        sh[threadIdx.x] = shft[b * 64 + threadIdx.x];
    }
    __syncthreads();
    long i0 = ((long)blockIdx.x * 256 + threadIdx.x) * 8;
    __hip_bfloat16 loc[8];
    *(frag8*)loc = *(const frag8*)(A + i0);
    int c0 = (int)(i0 & 63);
#pragma unroll
    for (int j = 0; j < 8; j++) {
        float f  = bf2f(loc[j]);
        float an = fmaf(f, sc[c0 + j], sh[c0 + j]);
        loc[j]   = f2bf(fmaxf(an, NEG_SLOPE * an));
    }
    *(frag8*)(A + i0) = *(frag8*)loc;
}

// ---------------------------------------------------------------------------
// conv2 via MFMA: M=pixels, N=32, K=192. XCD-chunked swizzle (4800 = 8x600).
// Residual add + coalesced store via padded LDS transpose.
// ---------------------------------------------------------------------------
__global__ __launch_bounds__(256) void conv2_mfma(
    const __hip_bfloat16* __restrict__ Aact,
    const __hip_bfloat16* __restrict__ Bp2,
    const float* __restrict__ b2,
    const float* __restrict__ x,
    float* __restrict__ out,
    int b)
{
    int wave = threadIdx.x >> 6;
    int lane = threadIdx.x & 63;
    int ml   = lane & 31;
    int kh   = lane >> 5;
    int bid  = blockIdx.x;
    int sw   = (bid & 7) * 600 + (bid >> 3);
    int tile = sw * 4 + wave;   // 0..19199

    frag8 bf[12];
#pragma unroll
    for (int kb = 0; kb < 12; kb++)
        bf[kb] = *(const frag8*)(Bp2 + (kb * 64 + lane) * 8);

    int d  = tile / 800;
    int p0 = (tile % 800) * 32;

    accf16 acc;
#pragma unroll
    for (int i = 0; i < 16; i++) acc[i] = 0.f;

    for (int kd = 0; kd < 3; kd++) {
        int dd = d + kd - 1;
        bool valid = (unsigned)dd < (unsigned)Dn;
        const __hip_bfloat16* rp = Aact + (long)dd * HWn * 64;
#pragma unroll
        for (int qq = 0; qq < 4; qq++) {
            frag8 a = {};
            if (valid)
                a = *(const frag8*)(rp + (long)(p0 + ml) * 64 + qq * 16 + kh * 8);
            acc = __builtin_amdgcn_mfma_f32_32x32x16_bf16(a, bf[kd * 4 + qq], acc, 0, 0, 0);
        }
    }

    __shared__ float tb[4][32][33];
    float bias = b2[ml];
    const float* xb = x   + (long)b * Cn * DHWn + (long)d * HWn;
    float*       ob = out + (long)b * Cn * DHWn + (long)d * HWn;
#pragma unroll
    for (int i = 0; i < 16; i++) {
        int row = (i & 3) + 8 * (i >> 2) + 4 * kh;
        tb[wave][row][ml] = acc[i] + bias;
    }
    // wave-private tile: same-wave DS ordering + compiler lgkmcnt waits
#pragma unroll
    for (int r2 = 0; r2 < 16; r2++) {
        int c = r2 * 2 + kh;
        float v = tb[wave][ml][c] + xb[(long)c * DHWn + p0 + ml];
        ob[(long)c * DHWn + p0 + ml] = v;
    }
}

// ---------------------------------------------------------------------------
// Persistent GRU: one launch, 24 steps x {r-phase, cand-phase}, grid barrier
// between phases. Block = 4 waves = 4 (dir,b) streams of the SAME 32-pixel
// tile; tile is XCD-chunked so each XCD's h/rh/hnew stays in its L2 for the
// whole scan. Requires all NBLK blocks co-resident (coop launch validates).
// ---------------------------------------------------------------------------
__global__ __launch_bounds__(256, 4) void gru_persist(
    const __hip_bfloat16* __restrict__ xhwc,
    const __hip_bfloat16* __restrict__ Bu,
    const __hip_bfloat16* __restrict__ Br,
    const __hip_bfloat16* __restrict__ Bo,
    const float* __restrict__ bu, const float* __restrict__ br,
    const float* __restrict__ bo,
    __hip_bfloat16* __restrict__ hA,
    __hip_bfloat16* __restrict__ hB,
    __hip_bfloat16* __restrict__ rhbf,
    float* __restrict__ out,
    int* __restrict__ bar)
{
    int wave = threadIdx.x >> 6;
    int lane = threadIdx.x & 63;
    int ml   = lane & 31;
    int kh   = lane >> 5;
    int bid  = blockIdx.x;
    int tile = (bid & 7) * 100 + (bid >> 3);   // XCD-chunked, bijective (800=8x100)
    int db   = wave;                            // dir*2 + b
    int dir  = db >> 1, b = db & 1;
    int pb   = tile * 32;                       // tile within one row (160%32==0)
    int py0  = pb / Wn, px0 = pb % Wn;

    __shared__ float tb[4][32][33];

    float bias_r = br[ml], bias_u = bu[ml], bias_o = bo[ml];
    __hip_bfloat16* rhb = rhbf + (long)db * HWn * 32;
    float* ob_base = out + (long)b * Cn * DHWn;

    int ph = 0;
    for (int s = 0; s < Dn; s++) {
        int d = dir ? (Dn - 1 - s) : s;
        const __hip_bfloat16* xb  = xhwc + ((long)b * Dn + d) * HWn * 32;
        const __hip_bfloat16* hb  = ((s & 1) ? hB : hA) + (long)db * HWn * 32;
        __hip_bfloat16*       hnb = ((s & 1) ? hA : hB) + (long)db * HWn * 32;

        // ---------------- phase A: r = sigm(conv([x,h])), write r*h --------
        {
            accf16 ar;
#pragma unroll
            for (int i = 0; i < 16; i++) ar[i] = 0.f;
            for (int tap = 0; tap < 9; tap++) {
                int dy = tap / 3 - 1, dx = tap % 3 - 1;
                int yy = py0 + dy, xx = px0 + ml + dx;
                bool ok = ((unsigned)yy < (unsigned)Hn) & ((unsigned)xx < (unsigned)Wn);
                long poff = ((long)(yy * Wn + xx)) * 32;
#pragma unroll
                for (int kb = 0; kb < 4; kb++) {
                    frag8 brf = *(const frag8*)(Br + ((tap * 4 + kb) * 64 + lane) * 8);
                    int ch = kb * 16 + kh * 8;
                    const __hip_bfloat16* bsel = (kb < 2) ? (xb + ch) : (hb + (ch - 32));
                    frag8 a = {};
                    if (ok) a = *(const frag8*)(bsel + poff);
                    ar = __builtin_amdgcn_mfma_f32_32x32x16_bf16(a, brf, ar, 0, 0, 0);
                }
            }
#pragma unroll
            for (int i = 0; i < 16; i++) {
                int row = (i & 3) + 8 * (i >> 2) + 4 * kh;
                int pix = pb + row;
                float hp = bf2f(hb[(long)pix * 32 + ml]);
                float rr = sigm(ar[i] + bias_r);
                rhb[(long)pix * 32 + ml] = f2bf(rr * hp);
            }
        }
        grid_barrier(bar, ++ph);

        // ------------- phase B: u, cand, h update, out accumulate ----------
        {
            accf16 au, ao;
#pragma unroll
            for (int i = 0; i < 16; i++) { au[i] = 0.f; ao[i] = 0.f; }
            for (int tap = 0; tap < 9; tap++) {
                int dy = tap / 3 - 1, dx = tap % 3 - 1;
                int yy = py0 + dy, xx = px0 + ml + dx;
                bool ok = ((unsigned)yy < (unsigned)Hn) & ((unsigned)xx < (unsigned)Wn);
                long poff = ((long)(yy * Wn + xx)) * 32;
#pragma unroll
                for (int kb = 0; kb < 4; kb++) {
                    frag8 buf = *(const frag8*)(Bu + ((tap * 4 + kb) * 64 + lane) * 8);
                    frag8 bof = *(const frag8*)(Bo + ((tap * 4 + kb) * 64 + lane) * 8);
                    int ch = kb * 16 + kh * 8;
                    if (kb < 2) {
                        frag8 a = {};
                        if (ok) a = *(const frag8*)(xb + ch + poff);
                        au = __builtin_amdgcn_mfma_f32_32x32x16_bf16(a, buf, au, 0, 0, 0);
                        ao = __builtin_amdgcn_mfma_f32_32x32x16_bf16(a, bof, ao, 0, 0, 0);
                    } else {
                        frag8 ah = {}, arh = {};
                        if (ok) {
                            ah  = *(const frag8*)(hb  + (ch - 32) + poff);
                            arh = *(const frag8*)(rhb + (ch - 32) + poff);
                        }
                        au = __builtin_amdgcn_mfma_f32_32x32x16_bf16(ah,  buf, au, 0, 0, 0);
                        ao = __builtin_amdgcn_mfma_f32_32x32x16_bf16(arh, bof, ao, 0, 0, 0);
                    }
                }
            }
            float* ob = ob_base + (long)d * HWn;
#pragma unroll
            for (int i = 0; i < 16; i++) {
                int row = (i & 3) + 8 * (i >> 2) + 4 * kh;
                int pix = pb + row;
                float uu = sigm(au[i] + bias_u);
                float cc = tanh_(ao[i] + bias_o);
                float hp = bf2f(hb[(long)pix * 32 + ml]);
                float hn = (1.f - uu) * hp + uu * cc;
                hnb[(long)pix * 32 + ml] = f2bf(hn);
                tb[wave][row][ml] = hn;
            }
#pragma unroll
            for (int r2 = 0; r2 < 16; r2++) {
                int c = r2 * 2 + kh;
                ob[(long)c * DHWn + pb + ml] += tb[wave][ml][c];
            }
        }
        grid_barrier(bar, ++ph);
    }
}

// ---------------------------------------------------------------------------
// Fallback (48-launch) GRU kernels — used only if cooperative launch fails.
// ---------------------------------------------------------------------------
__global__ __launch_bounds__(256) void gru_r_mfma(
    const __hip_bfloat16* __restrict__ xhwc,
    int dfwd, int dbwd,
    const __hip_bfloat16* __restrict__ hold,
    const __hip_bfloat16* __restrict__ Br,
    const float* __restrict__ br,
    __hip_bfloat16* __restrict__ rhbf)
{
    int db   = blockIdx.y;
    int dir  = db >> 1, b = db & 1;
    int d    = dir ? dbwd : dfwd;
    int wave = threadIdx.x >> 6;
    int lane = threadIdx.x & 63;
    int ml   = lane & 31;
    int kh   = lane >> 5;

    const __hip_bfloat16* xb = xhwc + ((long)b * Dn + d) * HWn * 32;
    const __hip_bfloat16* hb = hold + (long)db * HWn * 32;

    int tile = blockIdx.x * 4 + wave;
    int pb   = tile * 32;
    int py0  = pb / Wn, px0 = pb % Wn;

    accf16 ar;
#pragma unroll
    for (int i = 0; i < 16; i++) ar[i] = 0.f;

    for (int tap = 0; tap < 9; tap++) {
        int dy = tap / 3 - 1, dx = tap % 3 - 1;
        int yy = py0 + dy;
        int xx = px0 + ml + dx;
        bool ok  = ((unsigned)yy < (unsigned)Hn) & ((unsigned)xx < (unsigned)Wn);
        long poff = ((long)(yy * Wn + xx)) * 32;
#pragma unroll
        for (int kb = 0; kb < 4; kb++) {
            frag8 brf = *(const frag8*)(Br + ((tap * 4 + kb) * 64 + lane) * 8);
            int ch = kb * 16 + kh * 8;
            const __hip_bfloat16* bsel = (kb < 2) ? (xb + ch) : (hb + (ch - 32));
            frag8 a = {};
            if (ok) a = *(const frag8*)(bsel + poff);
            ar = __builtin_amdgcn_mfma_f32_32x32x16_bf16(a, brf, ar, 0, 0, 0);
        }
    }

    float bias_r = br[ml];
    __hip_bfloat16* rhb = rhbf + (long)db * HWn * 32;
#pragma unroll
    for (int i = 0; i < 16; i++) {
        int row = (i & 3) + 8 * (i >> 2) + 4 * kh;
        int pix = pb + row;
        float hp = bf2f(hb[(long)pix * 32 + ml]);
        float rr = sigm(ar[i] + bias_r);
        rhb[(long)pix * 32 + ml] = f2bf(rr * hp);
    }
}

__global__ __launch_bounds__(256) void gru_cand_mfma(
    const __hip_bfloat16* __restrict__ xhwc,
    int dfwd, int dbwd,
    const __hip_bfloat16* __restrict__ hold,
    const __hip_bfloat16* __restrict__ rhbf,
    const __hip_bfloat16* __restrict__ Bu,
    const __hip_bfloat16* __restrict__ Bo,
    const float* __restrict__ bu, const float* __restrict__ bo,
    __hip_bfloat16* __restrict__ hnew,
    float* __restrict__ out)
{
    int db   = blockIdx.y;
    int dir  = db >> 1, b = db & 1;
    int d    = dir ? dbwd : dfwd;
    int wave = threadIdx.x >> 6;
    int lane = threadIdx.x & 63;
    int ml   = lane & 31;
    int kh   = lane >> 5;

    const __hip_bfloat16* xb  = xhwc + ((long)b * Dn + d) * HWn * 32;
    const __hip_bfloat16* hb  = hold + (long)db * HWn * 32;
    const __hip_bfloat16* rhb = rhbf + (long)db * HWn * 32;
    __hip_bfloat16*       hnb = hnew + (long)db * HWn * 32;

    int tile = blockIdx.x * 4 + wave;
    int pb   = tile * 32;
    int py0  = pb / Wn, px0 = pb % Wn;

    accf16 au, ao;
#pragma unroll
    for (int i = 0; i < 16; i++) { au[i] = 0.f; ao[i] = 0.f; }

    for (int tap = 0; tap < 9; tap++) {
        int dy = tap / 3 - 1, dx = tap % 3 - 1;
        int yy = py0 + dy;
        int xx = px0 + ml + dx;
        bool ok  = ((unsigned)yy < (unsigned)Hn) & ((unsigned)xx < (unsigned)Wn);
        long poff = ((long)(yy * Wn + xx)) * 32;
#pragma unroll
        for (int kb = 0; kb < 4; kb++) {
            frag8 buf = *(const frag8*)(Bu + ((tap * 4 + kb) * 64 + lane) * 8);
            frag8 bof = *(const frag8*)(Bo + ((tap * 4 + kb) * 64 + lane) * 8);
            int ch = kb * 16 + kh * 8;
            if (kb < 2) {
                frag8 a = {};
                if (ok) a = *(const frag8*)(xb + ch + poff);
                au = __builtin_amdgcn_mfma_f32_32x32x16_bf16(a, buf, au, 0, 0, 0);
                ao = __builtin_amdgcn_mfma_f32_32x32x16_bf16(a, bof, ao, 0, 0, 0);
            } else {
                frag8 ah = {}, arh = {};
                if (ok) {
                    ah  = *(const frag8*)(hb  + (ch - 32) + poff);
                    arh = *(const frag8*)(rhb + (ch - 32) + poff);
                }
                au = __builtin_amdgcn_mfma_f32_32x32x16_bf16(ah,  buf, au, 0, 0, 0);
                ao = __builtin_amdgcn_mfma_f32_32x32x16_bf16(arh, bof, ao, 0, 0, 0);
            }
        }
    }

    __shared__ float tb[4][32][33];
    float bias_u = bu[ml], bias_o = bo[ml];
    float* ob = out + (long)b * Cn * DHWn + (long)d * HWn;
#pragma unroll
    for (int i = 0; i < 16; i++) {
        int row = (i & 3) + 8 * (i >> 2) + 4 * kh;
        int pix = pb + row;
        float uu = sigm(au[i] + bias_u);
        float cc = tanh_(ao[i] + bias_o);
        float hp = bf2f(hb[(long)pix * 32 + ml]);
        float hn = (1.f - uu) * hp + uu * cc;
        hnb[(long)pix * 32 + ml] = f2bf(hn);
        tb[wave][row][ml] = hn;
    }
#pragma unroll
    for (int r2 = 0; r2 < 16; r2++) {
        int c = r2 * 2 + kh;
        ob[(long)c * DHWn + pb + ml] += tb[wave][ml][c];
    }
}

// ---------------------------------------------------------------------------
extern "C" void kernel_launch(void* const* d_in, const int* in_sizes, int n_in,
                              void* d_out, int out_size, void* d_ws, size_t ws_size,
                              hipStream_t stream)
{
    const float* x    = (const float*)d_in[0];
    const float* w_f1 = (const float*)d_in[1];
    const float* b_f1 = (const float*)d_in[2];
    const float* gn_g = (const float*)d_in[3];
    const float* gn_b = (const float*)d_in[4];
    const float* w_f2 = (const float*)d_in[5];
    const float* b_f2 = (const float*)d_in[6];
    const float* w_u  = (const float*)d_in[7];
    const float* b_u  = (const float*)d_in[8];
    const float* w_r  = (const float*)d_in[9];
    const float* b_r  = (const float*)d_in[10];
    const float* w_o  = (const float*)d_in[11];
    const float* b_o  = (const float*)d_in[12];
    float* out = (float*)d_out;

    // ---- workspace layout ----
    char* ws = (char*)d_ws;
    __hip_bfloat16* Bp1 = (__hip_bfloat16*)ws;            // 6144 elems
    __hip_bfloat16* Bp2 = Bp1 + 6144;                     // 6144
    __hip_bfloat16* Bu  = Bp2 + 6144;                     // 18432 each
    __hip_bfloat16* Br  = Bu + 18432;
    __hip_bfloat16* Bo  = Br + 18432;
    float* gsum = (float*)(Bo + 18432);                   // 128
    float* gsq  = gsum + 128;                             // 128
    float* scal = gsq + 128;                              // 128
    float* shft = scal + 128;                             // 128
    int*   bar  = (int*)(shft + 128);                     // 2 ints
    char* big = (char*)(bar + 4);
    big = (char*)(((uintptr_t)big + 255) & ~(uintptr_t)255);

    __hip_bfloat16* xhwc = (__hip_bfloat16*)big;                  // 78,643,200 B
    __hip_bfloat16* Apre = (__hip_bfloat16*)(big + 78643200L);    // 78,643,200 B
    __hip_bfloat16* hA   = (__hip_bfloat16*)(big + 78643200L);    //  6,553,600 B
    __hip_bfloat16* hB   = (__hip_bfloat16*)(big + 85196800L);    //  6,553,600 B
    __hip_bfloat16* rhbf = (__hip_bfloat16*)(big + 91750400L);    //  6,553,600 B

    size_t need = (size_t)(big - ws) + 157286400UL;
    if (ws_size < need) return;  // workspace too small

    // ---- weight transforms ----
    bpack1_kernel<<<24, 256, 0, stream>>>(w_f1, Bp1);
    bpack2_kernel<<<24, 256, 0, stream>>>(w_f2, Bp2);
    bpack_kernel<<<72, 256, 0, stream>>>(w_u, Bu);
    bpack_kernel<<<72, 256, 0, stream>>>(w_r, Br);
    bpack_kernel<<<72, 256, 0, stream>>>(w_o, Bo);
    hipMemsetAsync(gsum, 0, 256 * sizeof(float), stream);  // gsum+gsq

    // ---- HWC transpose (feeds conv1 AND the GRU phase) ----
    tohwc_kernel<<<dim3(400, Bn * Dn), 256, 0, stream>>>(x, xhwc);

    // ---- slice_flow path via MFMA, one batch at a time (Apre reused) ----
    for (int b = 0; b < Bn; b++) {
        conv1_mfma<<<2400, 256, 0, stream>>>(xhwc, Bp1, b_f1, b, Apre, gsum, gsq);
        finalize_kernel<<<1, 64, 0, stream>>>(gsum, gsq, gn_g, gn_b, scal, shft, b);
        act_kernel<<<19200, 256, 0, stream>>>(Apre, scal, shft, b);
        conv2_mfma<<<4800, 256, 0, stream>>>(Apre, Bp2, b_f2, x, out, b);
    }

    // ---- GRU phase: persistent cooperative kernel ----
    hipMemsetAsync(bar, 0, 2 * sizeof(int), stream);  // reset barrier each replay
    hipMemsetAsync(hA, 0, 6553600, stream);

    void* args[] = { (void*)&xhwc, (void*)&Bu, (void*)&Br, (void*)&Bo,
                     (void*)&b_u, (void*)&b_r, (void*)&b_o,
                     (void*)&hA, (void*)&hB, (void*)&rhbf,
                     (void*)&out, (void*)&bar };
    hipError_t rc = hipLaunchCooperativeKernel(
        reinterpret_cast<void*>(gru_persist), dim3(NBLK), dim3(256),
        args, 0, stream);

    if (rc != hipSuccess) {
        // Fallback: 48-launch double-buffered path (same math).
        __hip_bfloat16* hbufs[2] = { hA, hB };
        for (int s = 0; s < Dn; s++) {
            int dfwd = s, dbwd = Dn - 1 - s;
            __hip_bfloat16* hold = hbufs[s & 1];
            __hip_bfloat16* hnew = hbufs[(s + 1) & 1];
            gru_r_mfma<<<dim3(200, 4), 256, 0, stream>>>(
                xhwc, dfwd, dbwd, hold, Br, b_r, rhbf);
            gru_cand_mfma<<<dim3(200, 4), 256, 0, stream>>>(
                xhwc, dfwd, dbwd, hold, rhbf, Bu, Bo, b_u, b_o, hnew, out);
        }
    }
}

// Round 4
// 9422.504 us; speedup vs baseline: 1.3685x; 1.3685x over previous
//
#include <hip/hip_runtime.h>
#include <hip/hip_bf16.h>
#include <stdint.h>

#define EPS_GN 1e-5f
#define NEG_SLOPE 0.2f

static constexpr int  Bn   = 2;
static constexpr int  Cn   = 32;
static constexpr int  Dn   = 24;
static constexpr int  Hn   = 160;
static constexpr int  Wn   = 160;
static constexpr int  HWn  = Hn * Wn;              // 25600
static constexpr long DHWn = (long)Dn * HWn;       // 614400
static constexpr long NPIX = (long)Bn * Dn * HWn;  // 1228800
static constexpr int  NBLK = 800;                  // persistent GRU grid

using frag8  = __attribute__((ext_vector_type(8)))  short;  // 8 bf16 (4 VGPRs)
using accf16 = __attribute__((ext_vector_type(16))) float;  // 32x32 C/D frag

__device__ __forceinline__ float bf2f(__hip_bfloat16 v) { return __bfloat162float(v); }
__device__ __forceinline__ __hip_bfloat16 f2bf(float v) { return __float2bfloat16(v); }
__device__ __forceinline__ float sigm(float v) { return 1.f / (1.f + __expf(-v)); }
__device__ __forceinline__ float tanh_(float v) {
    float e = __expf(2.f * v);
    return 1.f - 2.f / (e + 1.f);
}

// ---------------------------------------------------------------------------
// Grid-wide barrier. bar[0]=arrival, bar[1]=phase (monotonic).
// KEY: poll with RELAXED loads (no per-iteration cache invalidate — an
// agent-scope ACQUIRE load emits buffer_inv each poll, which was nuking
// every XCD L2 continuously in the previous round). One __threadfence()
// (acquire+wbinv) after the flag is observed gives the needed coherence.
// ---------------------------------------------------------------------------
__device__ __forceinline__ void grid_barrier(int* bar, int ph) {
    __syncthreads();
    if (threadIdx.x == 0) {
        __threadfence();   // release: write back our h/rh/out before arrival
        int n = __hip_atomic_fetch_add(&bar[0], 1, __ATOMIC_ACQ_REL, __HIP_MEMORY_SCOPE_AGENT);
        if (n == NBLK - 1) {
            __hip_atomic_store(&bar[0], 0, __ATOMIC_RELAXED, __HIP_MEMORY_SCOPE_AGENT);
            __hip_atomic_store(&bar[1], ph, __ATOMIC_RELEASE, __HIP_MEMORY_SCOPE_AGENT);
        } else {
            while (__hip_atomic_load(&bar[1], __ATOMIC_RELAXED, __HIP_MEMORY_SCOPE_AGENT) < ph)
                __builtin_amdgcn_s_sleep(8);
        }
        __threadfence();   // acquire: invalidate stale lines ONCE per phase
    }
    __syncthreads();
}

// ---------------------------------------------------------------------------
// Pack conv1 weight w_f1 [64][32][3] into MFMA B-frag order.
// ---------------------------------------------------------------------------
__global__ __launch_bounds__(256) void bpack1_kernel(
    const float* __restrict__ w, __hip_bfloat16* __restrict__ dst)
{
    int t = blockIdx.x * 256 + threadIdx.x;
    if (t >= 6 * 2 * 64 * 8) return;
    int j    = t & 7;
    int lane = (t >> 3) & 63;
    int idx  = t >> 9;           // kb*2+nt
    int nt   = idx & 1;
    int kb   = idx >> 1;         // 0..5
    int o    = nt * 32 + (lane & 31);
    int k    = kb * 16 + (lane >> 5) * 8 + j;
    int ci   = k & 31;
    int kd   = k >> 5;
    dst[t] = f2bf(w[(o * 32 + ci) * 3 + kd]);
}

// ---------------------------------------------------------------------------
// Pack conv2 weight w_f2 [32][64][3]. K-order: k = kd*64 + ci.
// ---------------------------------------------------------------------------
__global__ __launch_bounds__(256) void bpack2_kernel(
    const float* __restrict__ w, __hip_bfloat16* __restrict__ dst)
{
    int t = blockIdx.x * 256 + threadIdx.x;
    if (t >= 12 * 64 * 8) return;
    int j    = t & 7;
    int lane = (t >> 3) & 63;
    int kb   = t >> 9;           // 0..11
    int o    = lane & 31;
    int k    = kb * 16 + (lane >> 5) * 8 + j;
    int ci   = k & 63;
    int kd   = k >> 6;
    dst[t] = f2bf(w[(o * 64 + ci) * 3 + kd]);
}

// ---------------------------------------------------------------------------
// Pack GRU conv weight [32][64][3][3] fp32 into MFMA B-fragment lane order.
// ---------------------------------------------------------------------------
__global__ __launch_bounds__(256) void bpack_kernel(
    const float* __restrict__ w, __hip_bfloat16* __restrict__ dst)
{
    int t = blockIdx.x * 256 + threadIdx.x;
    if (t >= 9 * 4 * 64 * 8) return;
    int j    = t & 7;
    int lane = (t >> 3) & 63;
    int kb   = (t >> 9) & 3;
    int tap  = t >> 11;
    int ci   = kb * 16 + (lane >> 5) * 8 + j;
    int o    = lane & 31;
    dst[t] = f2bf(w[(o * 64 + ci) * 9 + tap]);
}

// ---------------------------------------------------------------------------
// x [B][C][D][HW] fp32 -> xhwc [B][D][HW][32] bf16 via LDS transpose tile.
// ---------------------------------------------------------------------------
__global__ __launch_bounds__(256) void tohwc_kernel(
    const float* __restrict__ x, __hip_bfloat16* __restrict__ xhwc)
{
    __shared__ float tile[32][65];
    int bd = blockIdx.y;            // b*Dn+d
    int b  = bd / Dn, d = bd % Dn;
    int p0 = blockIdx.x * 64;
    const float* xb = x + (long)b * Cn * DHWn + (long)d * HWn + p0;
    for (int e = threadIdx.x; e < 2048; e += 256) {
        int c = e >> 6, p = e & 63;
        tile[c][p] = xb[(long)c * DHWn + p];
    }
    __syncthreads();
    __hip_bfloat16* ob = xhwc + ((long)bd * HWn + p0) * 32;
    for (int e = threadIdx.x; e < 2048; e += 256) {
        int p = e >> 5, c = e & 31;
        ob[p * 32 + c] = f2bf(tile[c][p]);
    }
}

// ---------------------------------------------------------------------------
// conv1 via MFMA: M=pixels (32/tile), N=64, K=96. GN stats fused.
// XCD-chunked block swizzle (2400 = 8 x 300) for d-slice L2 locality.
// ---------------------------------------------------------------------------
__global__ __launch_bounds__(256) void conv1_mfma(
    const __hip_bfloat16* __restrict__ xhwc,
    const __hip_bfloat16* __restrict__ Bp1,
    const float* __restrict__ b1,
    int b,
    __hip_bfloat16* __restrict__ A,
    float* __restrict__ gsum, float* __restrict__ gsq)
{
    int wave = threadIdx.x >> 6;
    int lane = threadIdx.x & 63;
    int ml   = lane & 31;
    int kh   = lane >> 5;
    int bid  = blockIdx.x;
    int sw   = (bid & 7) * 300 + (bid >> 3);
    int tile0 = sw * 8 + wave * 2;   // even; 800 tiles per d-slice

    frag8 bf[6][2];
#pragma unroll
    for (int kb = 0; kb < 6; kb++)
#pragma unroll
        for (int nt = 0; nt < 2; nt++)
            bf[kb][nt] = *(const frag8*)(Bp1 + ((kb * 2 + nt) * 64 + lane) * 8);

    int d  = tile0 / 800;
    int p0 = (tile0 % 800) * 32;

    accf16 acc[2][2];
#pragma unroll
    for (int t = 0; t < 2; t++)
#pragma unroll
        for (int nt = 0; nt < 2; nt++)
#pragma unroll
            for (int i = 0; i < 16; i++) acc[t][nt][i] = 0.f;

    for (int kd = 0; kd < 3; kd++) {
        int dd = d + kd - 1;
        bool valid = (unsigned)dd < (unsigned)Dn;
        const __hip_bfloat16* rp = xhwc + ((long)(b * Dn + dd) * HWn) * 32;
#pragma unroll
        for (int h2 = 0; h2 < 2; h2++) {
            int kb = kd * 2 + h2;
#pragma unroll
            for (int t = 0; t < 2; t++) {
                frag8 a = {};
                if (valid)
                    a = *(const frag8*)(rp + (long)(p0 + t * 32 + ml) * 32 + h2 * 16 + kh * 8);
                acc[t][0] = __builtin_amdgcn_mfma_f32_32x32x16_bf16(a, bf[kb][0], acc[t][0], 0, 0, 0);
                acc[t][1] = __builtin_amdgcn_mfma_f32_32x32x16_bf16(a, bf[kb][1], acc[t][1], 0, 0, 0);
            }
        }
    }

    float bias[2] = { b1[ml], b1[32 + ml] };
    float s[2] = {0.f, 0.f}, q[2] = {0.f, 0.f};
    __hip_bfloat16* Ap = A + (long)d * HWn * 64;
#pragma unroll
    for (int t = 0; t < 2; t++) {
        int pb = p0 + t * 32;
#pragma unroll
        for (int nt = 0; nt < 2; nt++) {
#pragma unroll
            for (int i = 0; i < 16; i++) {
                int row = (i & 3) + 8 * (i >> 2) + 4 * kh;
                float v = acc[t][nt][i] + bias[nt];
                Ap[(long)(pb + row) * 64 + nt * 32 + ml] = f2bf(v);
                s[nt] += v;
                q[nt] += v * v;
            }
        }
    }
#pragma unroll
    for (int nt = 0; nt < 2; nt++) {
        s[nt] += __shfl_xor(s[nt], 32);
        q[nt] += __shfl_xor(q[nt], 32);
    }
    __shared__ float ss[64], sq[64];
    if (threadIdx.x < 64) { ss[threadIdx.x] = 0.f; sq[threadIdx.x] = 0.f; }
    __syncthreads();
    if (lane < 32) {
        atomicAdd(&ss[ml],      s[0]); atomicAdd(&sq[ml],      q[0]);
        atomicAdd(&ss[32 + ml], s[1]); atomicAdd(&sq[32 + ml], q[1]);
    }
    __syncthreads();
    if (threadIdx.x < 64) {
        atomicAdd(&gsum[b * 64 + threadIdx.x], ss[threadIdx.x]);
        atomicAdd(&gsq [b * 64 + threadIdx.x], sq[threadIdx.x]);
    }
}

__global__ __launch_bounds__(64) void finalize_kernel(
    const float* __restrict__ gsum, const float* __restrict__ gsq,
    const float* __restrict__ gn_g, const float* __restrict__ gn_b,
    float* __restrict__ scal, float* __restrict__ shft, int b)
{
    int ci = threadIdx.x;
    if (ci >= 64) return;
    int g = ci >> 3;
    float s = 0.f, qq = 0.f;
#pragma unroll
    for (int k = 0; k < 8; k++) {
        s  += gsum[b * 64 + g * 8 + k];
        qq += gsq [b * 64 + g * 8 + k];
    }
    float N   = 8.0f * (float)DHWn;
    float mu  = s / N;
    float var = qq / N - mu * mu;
    float rs  = rsqrtf(var + EPS_GN);
    float scv = rs * gn_g[ci];
    scal[b * 64 + ci] = scv;
    shft[b * 64 + ci] = gn_b[ci] - mu * scv;
}

// ---------------------------------------------------------------------------
// In-place GN affine + LeakyReLU on A [D][HW][64] bf16 (one batch).
// ---------------------------------------------------------------------------
__global__ __launch_bounds__(256) void act_kernel(
    __hip_bfloat16* __restrict__ A,
    const float* __restrict__ scal, const float* __restrict__ shft, int b)
{
    __shared__ float sc[64], sh[64];
    if (threadIdx.x < 64) {
        sc[threadIdx.x] = scal[b * 64 + threadIdx.x];
        sh[threadIdx.x] = shft[b * 64 + threadIdx.x];
    }
    __syncthreads();
    long i0 = ((long)blockIdx.x * 256 + threadIdx.x) * 8;
    __hip_bfloat16 loc[8];
    *(frag8*)loc = *(const frag8*)(A + i0);
    int c0 = (int)(i0 & 63);
#pragma unroll
    for (int j = 0; j < 8; j++) {
        float f  = bf2f(loc[j]);
        float an = fmaf(f, sc[c0 + j], sh[c0 + j]);
        loc[j]   = f2bf(fmaxf(an, NEG_SLOPE * an));
    }
    *(frag8*)(A + i0) = *(frag8*)loc;
}

// ---------------------------------------------------------------------------
// conv2 via MFMA: M=pixels, N=32, K=192. XCD-chunked swizzle (4800 = 8x600).
// Residual add + coalesced store via padded LDS transpose.
// ---------------------------------------------------------------------------
__global__ __launch_bounds__(256) void conv2_mfma(
    const __hip_bfloat16* __restrict__ Aact,
    const __hip_bfloat16* __restrict__ Bp2,
    const float* __restrict__ b2,
    const float* __restrict__ x,
    float* __restrict__ out,
    int b)
{
    int wave = threadIdx.x >> 6;
    int lane = threadIdx.x & 63;
    int ml   = lane & 31;
    int kh   = lane >> 5;
    int bid  = blockIdx.x;
    int sw   = (bid & 7) * 600 + (bid >> 3);
    int tile = sw * 4 + wave;   // 0..19199

    frag8 bf[12];
#pragma unroll
    for (int kb = 0; kb < 12; kb++)
        bf[kb] = *(const frag8*)(Bp2 + (kb * 64 + lane) * 8);

    int d  = tile / 800;
    int p0 = (tile % 800) * 32;

    accf16 acc;
#pragma unroll
    for (int i = 0; i < 16; i++) acc[i] = 0.f;

    for (int kd = 0; kd < 3; kd++) {
        int dd = d + kd - 1;
        bool valid = (unsigned)dd < (unsigned)Dn;
        const __hip_bfloat16* rp = Aact + (long)dd * HWn * 64;
#pragma unroll
        for (int qq = 0; qq < 4; qq++) {
            frag8 a = {};
            if (valid)
                a = *(const frag8*)(rp + (long)(p0 + ml) * 64 + qq * 16 + kh * 8);
            acc = __builtin_amdgcn_mfma_f32_32x32x16_bf16(a, bf[kd * 4 + qq], acc, 0, 0, 0);
        }
    }

    __shared__ float tb[4][32][33];
    float bias = b2[ml];
    const float* xb = x   + (long)b * Cn * DHWn + (long)d * HWn;
    float*       ob = out + (long)b * Cn * DHWn + (long)d * HWn;
#pragma unroll
    for (int i = 0; i < 16; i++) {
        int row = (i & 3) + 8 * (i >> 2) + 4 * kh;
        tb[wave][row][ml] = acc[i] + bias;
    }
    // wave-private tile: same-wave DS ordering + compiler lgkmcnt waits
#pragma unroll
    for (int r2 = 0; r2 < 16; r2++) {
        int c = r2 * 2 + kh;
        float v = tb[wave][ml][c] + xb[(long)c * DHWn + p0 + ml];
        ob[(long)c * DHWn + p0 + ml] = v;
    }
}

// ---------------------------------------------------------------------------
// Persistent GRU: one launch, 24 steps x {r-phase, cand-phase}, grid barrier
// between phases. Block = 4 waves = 4 (dir,b) streams of the SAME 32-pixel
// tile; tile is XCD-chunked so each XCD's h/rh/hnew stays in its L2 for the
// whole scan. Requires all NBLK blocks co-resident (coop launch validates).
// ---------------------------------------------------------------------------
__global__ __launch_bounds__(256, 4) void gru_persist(
    const __hip_bfloat16* __restrict__ xhwc,
    const __hip_bfloat16* __restrict__ Bu,
    const __hip_bfloat16* __restrict__ Br,
    const __hip_bfloat16* __restrict__ Bo,
    const float* __restrict__ bu, const float* __restrict__ br,
    const float* __restrict__ bo,
    __hip_bfloat16* __restrict__ hA,
    __hip_bfloat16* __restrict__ hB,
    __hip_bfloat16* __restrict__ rhbf,
    float* __restrict__ out,
    int* __restrict__ bar)
{
    int wave = threadIdx.x >> 6;
    int lane = threadIdx.x & 63;
    int ml   = lane & 31;
    int kh   = lane >> 5;
    int bid  = blockIdx.x;
    int tile = (bid & 7) * 100 + (bid >> 3);   // XCD-chunked, bijective (800=8x100)
    int db   = wave;                            // dir*2 + b
    int dir  = db >> 1, b = db & 1;
    int pb   = tile * 32;                       // tile within one row (160%32==0)
    int py0  = pb / Wn, px0 = pb % Wn;

    __shared__ float tb[4][32][33];

    float bias_r = br[ml], bias_u = bu[ml], bias_o = bo[ml];
    __hip_bfloat16* rhb = rhbf + (long)db * HWn * 32;
    float* ob_base = out + (long)b * Cn * DHWn;

    int ph = 0;
    for (int s = 0; s < Dn; s++) {
        int d = dir ? (Dn - 1 - s) : s;
        const __hip_bfloat16* xb  = xhwc + ((long)b * Dn + d) * HWn * 32;
        const __hip_bfloat16* hb  = ((s & 1) ? hB : hA) + (long)db * HWn * 32;
        __hip_bfloat16*       hnb = ((s & 1) ? hA : hB) + (long)db * HWn * 32;

        // ---------------- phase A: r = sigm(conv([x,h])), write r*h --------
        {
            accf16 ar;
#pragma unroll
            for (int i = 0; i < 16; i++) ar[i] = 0.f;
            for (int tap = 0; tap < 9; tap++) {
                int dy = tap / 3 - 1, dx = tap % 3 - 1;
                int yy = py0 + dy, xx = px0 + ml + dx;
                bool ok = ((unsigned)yy < (unsigned)Hn) & ((unsigned)xx < (unsigned)Wn);
                long poff = ((long)(yy * Wn + xx)) * 32;
#pragma unroll
                for (int kb = 0; kb < 4; kb++) {
                    frag8 brf = *(const frag8*)(Br + ((tap * 4 + kb) * 64 + lane) * 8);
                    int ch = kb * 16 + kh * 8;
                    const __hip_bfloat16* bsel = (kb < 2) ? (xb + ch) : (hb + (ch - 32));
                    frag8 a = {};
                    if (ok) a = *(const frag8*)(bsel + poff);
                    ar = __builtin_amdgcn_mfma_f32_32x32x16_bf16(a, brf, ar, 0, 0, 0);
                }
            }
#pragma unroll
            for (int i = 0; i < 16; i++) {
                int row = (i & 3) + 8 * (i >> 2) + 4 * kh;
                int pix = pb + row;
                float hp = bf2f(hb[(long)pix * 32 + ml]);
                float rr = sigm(ar[i] + bias_r);
                rhb[(long)pix * 32 + ml] = f2bf(rr * hp);
            }
        }
        grid_barrier(bar, ++ph);

        // ------------- phase B: u, cand, h update, out accumulate ----------
        {
            accf16 au, ao;
#pragma unroll
            for (int i = 0; i < 16; i++) { au[i] = 0.f; ao[i] = 0.f; }
            for (int tap = 0; tap < 9; tap++) {
                int dy = tap / 3 - 1, dx = tap % 3 - 1;
                int yy = py0 + dy, xx = px0 + ml + dx;
                bool ok = ((unsigned)yy < (unsigned)Hn) & ((unsigned)xx < (unsigned)Wn);
                long poff = ((long)(yy * Wn + xx)) * 32;
#pragma unroll
                for (int kb = 0; kb < 4; kb++) {
                    frag8 buf = *(const frag8*)(Bu + ((tap * 4 + kb) * 64 + lane) * 8);
                    frag8 bof = *(const frag8*)(Bo + ((tap * 4 + kb) * 64 + lane) * 8);
                    int ch = kb * 16 + kh * 8;
                    if (kb < 2) {
                        frag8 a = {};
                        if (ok) a = *(const frag8*)(xb + ch + poff);
                        au = __builtin_amdgcn_mfma_f32_32x32x16_bf16(a, buf, au, 0, 0, 0);
                        ao = __builtin_amdgcn_mfma_f32_32x32x16_bf16(a, bof, ao, 0, 0, 0);
                    } else {
                        frag8 ah = {}, arh = {};
                        if (ok) {
                            ah  = *(const frag8*)(hb  + (ch - 32) + poff);
                            arh = *(const frag8*)(rhb + (ch - 32) + poff);
                        }
                        au = __builtin_amdgcn_mfma_f32_32x32x16_bf16(ah,  buf, au, 0, 0, 0);
                        ao = __builtin_amdgcn_mfma_f32_32x32x16_bf16(arh, bof, ao, 0, 0, 0);
                    }
                }
            }
            float* ob = ob_base + (long)d * HWn;
#pragma unroll
            for (int i = 0; i < 16; i++) {
                int row = (i & 3) + 8 * (i >> 2) + 4 * kh;
                int pix = pb + row;
                float uu = sigm(au[i] + bias_u);
                float cc = tanh_(ao[i] + bias_o);
                float hp = bf2f(hb[(long)pix * 32 + ml]);
                float hn = (1.f - uu) * hp + uu * cc;
                hnb[(long)pix * 32 + ml] = f2bf(hn);
                tb[wave][row][ml] = hn;
            }
#pragma unroll
            for (int r2 = 0; r2 < 16; r2++) {
                int c = r2 * 2 + kh;
                ob[(long)c * DHWn + pb + ml] += tb[wave][ml][c];
            }
        }
        grid_barrier(bar, ++ph);
    }
}

// ---------------------------------------------------------------------------
// Fallback (48-launch) GRU kernels — used only if cooperative launch fails.
// ---------------------------------------------------------------------------
__global__ __launch_bounds__(256) void gru_r_mfma(
    const __hip_bfloat16* __restrict__ xhwc,
    int dfwd, int dbwd,
    const __hip_bfloat16* __restrict__ hold,
    const __hip_bfloat16* __restrict__ Br,
    const float* __restrict__ br,
    __hip_bfloat16* __restrict__ rhbf)
{
    int db   = blockIdx.y;
    int dir  = db >> 1, b = db & 1;
    int d    = dir ? dbwd : dfwd;
    int wave = threadIdx.x >> 6;
    int lane = threadIdx.x & 63;
    int ml   = lane & 31;
    int kh   = lane >> 5;

    const __hip_bfloat16* xb = xhwc + ((long)b * Dn + d) * HWn * 32;
    const __hip_bfloat16* hb = hold + (long)db * HWn * 32;

    int tile = blockIdx.x * 4 + wave;
    int pb   = tile * 32;
    int py0  = pb / Wn, px0 = pb % Wn;

    accf16 ar;
#pragma unroll
    for (int i = 0; i < 16; i++) ar[i] = 0.f;

    for (int tap = 0; tap < 9; tap++) {
        int dy = tap / 3 - 1, dx = tap % 3 - 1;
        int yy = py0 + dy;
        int xx = px0 + ml + dx;
        bool ok  = ((unsigned)yy < (unsigned)Hn) & ((unsigned)xx < (unsigned)Wn);
        long poff = ((long)(yy * Wn + xx)) * 32;
#pragma unroll
        for (int kb = 0; kb < 4; kb++) {
            frag8 brf = *(const frag8*)(Br + ((tap * 4 + kb) * 64 + lane) * 8);
            int ch = kb * 16 + kh * 8;
            const __hip_bfloat16* bsel = (kb < 2) ? (xb + ch) : (hb + (ch - 32));
            frag8 a = {};
            if (ok) a = *(const frag8*)(bsel + poff);
            ar = __builtin_amdgcn_mfma_f32_32x32x16_bf16(a, brf, ar, 0, 0, 0);
        }
    }

    float bias_r = br[ml];
    __hip_bfloat16* rhb = rhbf + (long)db * HWn * 32;
#pragma unroll
    for (int i = 0; i < 16; i++) {
        int row = (i & 3) + 8 * (i >> 2) + 4 * kh;
        int pix = pb + row;
        float hp = bf2f(hb[(long)pix * 32 + ml]);
        float rr = sigm(ar[i] + bias_r);
        rhb[(long)pix * 32 + ml] = f2bf(rr * hp);
    }
}

__global__ __launch_bounds__(256) void gru_cand_mfma(
    const __hip_bfloat16* __restrict__ xhwc,
    int dfwd, int dbwd,
    const __hip_bfloat16* __restrict__ hold,
    const __hip_bfloat16* __restrict__ rhbf,
    const __hip_bfloat16* __restrict__ Bu,
    const __hip_bfloat16* __restrict__ Bo,
    const float* __restrict__ bu, const float* __restrict__ bo,
    __hip_bfloat16* __restrict__ hnew,
    float* __restrict__ out)
{
    int db   = blockIdx.y;
    int dir  = db >> 1, b = db & 1;
    int d    = dir ? dbwd : dfwd;
    int wave = threadIdx.x >> 6;
    int lane = threadIdx.x & 63;
    int ml   = lane & 31;
    int kh   = lane >> 5;

    const __hip_bfloat16* xb  = xhwc + ((long)b * Dn + d) * HWn * 32;
    const __hip_bfloat16* hb  = hold + (long)db * HWn * 32;
    const __hip_bfloat16* rhb = rhbf + (long)db * HWn * 32;
    __hip_bfloat16*       hnb = hnew + (long)db * HWn * 32;

    int tile = blockIdx.x * 4 + wave;
    int pb   = tile * 32;
    int py0  = pb / Wn, px0 = pb % Wn;

    accf16 au, ao;
#pragma unroll
    for (int i = 0; i < 16; i++) { au[i] = 0.f; ao[i] = 0.f; }

    for (int tap = 0; tap < 9; tap++) {
        int dy = tap / 3 - 1, dx = tap % 3 - 1;
        int yy = py0 + dy;
        int xx = px0 + ml + dx;
        bool ok  = ((unsigned)yy < (unsigned)Hn) & ((unsigned)xx < (unsigned)Wn);
        long poff = ((long)(yy * Wn + xx)) * 32;
#pragma unroll
        for (int kb = 0; kb < 4; kb++) {
            frag8 buf = *(const frag8*)(Bu + ((tap * 4 + kb) * 64 + lane) * 8);
            frag8 bof = *(const frag8*)(Bo + ((tap * 4 + kb) * 64 + lane) * 8);
            int ch = kb * 16 + kh * 8;
            if (kb < 2) {
                frag8 a = {};
                if (ok) a = *(const frag8*)(xb + ch + poff);
                au = __builtin_amdgcn_mfma_f32_32x32x16_bf16(a, buf, au, 0, 0, 0);
                ao = __builtin_amdgcn_mfma_f32_32x32x16_bf16(a, bof, ao, 0, 0, 0);
            } else {
                frag8 ah = {}, arh = {};
                if (ok) {
                    ah  = *(const frag8*)(hb  + (ch - 32) + poff);
                    arh = *(const frag8*)(rhb + (ch - 32) + poff);
                }
                au = __builtin_amdgcn_mfma_f32_32x32x16_bf16(ah,  buf, au, 0, 0, 0);
                ao = __builtin_amdgcn_mfma_f32_32x32x16_bf16(arh, bof, ao, 0, 0, 0);
            }
        }
    }

    __shared__ float tb[4][32][33];
    float bias_u = bu[ml], bias_o = bo[ml];
    float* ob = out + (long)b * Cn * DHWn + (long)d * HWn;
#pragma unroll
    for (int i = 0; i < 16; i++) {
        int row = (i & 3) + 8 * (i >> 2) + 4 * kh;
        int pix = pb + row;
        float uu = sigm(au[i] + bias_u);
        float cc = tanh_(ao[i] + bias_o);
        float hp = bf2f(hb[(long)pix * 32 + ml]);
        float hn = (1.f - uu) * hp + uu * cc;
        hnb[(long)pix * 32 + ml] = f2bf(hn);
        tb[wave][row][ml] = hn;
    }
#pragma unroll
    for (int r2 = 0; r2 < 16; r2++) {
        int c = r2 * 2 + kh;
        ob[(long)c * DHWn + pb + ml] += tb[wave][ml][c];
    }
}

// ---------------------------------------------------------------------------
extern "C" void kernel_launch(void* const* d_in, const int* in_sizes, int n_in,
                              void* d_out, int out_size, void* d_ws, size_t ws_size,
                              hipStream_t stream)
{
    const float* x    = (const float*)d_in[0];
    const float* w_f1 = (const float*)d_in[1];
    const float* b_f1 = (const float*)d_in[2];
    const float* gn_g = (const float*)d_in[3];
    const float* gn_b = (const float*)d_in[4];
    const float* w_f2 = (const float*)d_in[5];
    const float* b_f2 = (const float*)d_in[6];
    const float* w_u  = (const float*)d_in[7];
    const float* b_u  = (const float*)d_in[8];
    const float* w_r  = (const float*)d_in[9];
    const float* b_r  = (const float*)d_in[10];
    const float* w_o  = (const float*)d_in[11];
    const float* b_o  = (const float*)d_in[12];
    float* out = (float*)d_out;

    // ---- workspace layout ----
    char* ws = (char*)d_ws;
    __hip_bfloat16* Bp1 = (__hip_bfloat16*)ws;            // 6144 elems
    __hip_bfloat16* Bp2 = Bp1 + 6144;                     // 6144
    __hip_bfloat16* Bu  = Bp2 + 6144;                     // 18432 each
    __hip_bfloat16* Br  = Bu + 18432;
    __hip_bfloat16* Bo  = Br + 18432;
    float* gsum = (float*)(Bo + 18432);                   // 128
    float* gsq  = gsum + 128;                             // 128
    float* scal = gsq + 128;                              // 128
    float* shft = scal + 128;                             // 128
    int*   bar  = (int*)(shft + 128);                     // 2 ints
    char* big = (char*)(bar + 4);
    big = (char*)(((uintptr_t)big + 255) & ~(uintptr_t)255);

    __hip_bfloat16* xhwc = (__hip_bfloat16*)big;                  // 78,643,200 B
    __hip_bfloat16* Apre = (__hip_bfloat16*)(big + 78643200L);    // 78,643,200 B
    __hip_bfloat16* hA   = (__hip_bfloat16*)(big + 78643200L);    //  6,553,600 B
    __hip_bfloat16* hB   = (__hip_bfloat16*)(big + 85196800L);    //  6,553,600 B
    __hip_bfloat16* rhbf = (__hip_bfloat16*)(big + 91750400L);    //  6,553,600 B

    size_t need = (size_t)(big - ws) + 157286400UL;
    if (ws_size < need) return;  // workspace too small

    // ---- weight transforms ----
    bpack1_kernel<<<24, 256, 0, stream>>>(w_f1, Bp1);
    bpack2_kernel<<<24, 256, 0, stream>>>(w_f2, Bp2);
    bpack_kernel<<<72, 256, 0, stream>>>(w_u, Bu);
    bpack_kernel<<<72, 256, 0, stream>>>(w_r, Br);
    bpack_kernel<<<72, 256, 0, stream>>>(w_o, Bo);
    hipMemsetAsync(gsum, 0, 256 * sizeof(float), stream);  // gsum+gsq

    // ---- HWC transpose (feeds conv1 AND the GRU phase) ----
    tohwc_kernel<<<dim3(400, Bn * Dn), 256, 0, stream>>>(x, xhwc);

    // ---- slice_flow path via MFMA, one batch at a time (Apre reused) ----
    for (int b = 0; b < Bn; b++) {
        conv1_mfma<<<2400, 256, 0, stream>>>(xhwc, Bp1, b_f1, b, Apre, gsum, gsq);
        finalize_kernel<<<1, 64, 0, stream>>>(gsum, gsq, gn_g, gn_b, scal, shft, b);
        act_kernel<<<19200, 256, 0, stream>>>(Apre, scal, shft, b);
        conv2_mfma<<<4800, 256, 0, stream>>>(Apre, Bp2, b_f2, x, out, b);
    }

    // ---- GRU phase: persistent cooperative kernel ----
    hipMemsetAsync(bar, 0, 2 * sizeof(int), stream);  // reset barrier each replay
    hipMemsetAsync(hA, 0, 6553600, stream);

    void* args[] = { (void*)&xhwc, (void*)&Bu, (void*)&Br, (void*)&Bo,
                     (void*)&b_u, (void*)&b_r, (void*)&b_o,
                     (void*)&hA, (void*)&hB, (void*)&rhbf,
                     (void*)&out, (void*)&bar };
    hipError_t rc = hipLaunchCooperativeKernel(
        reinterpret_cast<void*>(gru_persist), dim3(NBLK), dim3(256),
        args, 0, stream);

    if (rc != hipSuccess) {
        // Fallback: 48-launch double-buffered path (same math).
        __hip_bfloat16* hbufs[2] = { hA, hB };
        for (int s = 0; s < Dn; s++) {
            int dfwd = s, dbwd = Dn - 1 - s;
            __hip_bfloat16* hold = hbufs[s & 1];
            __hip_bfloat16* hnew = hbufs[(s + 1) & 1];
            gru_r_mfma<<<dim3(200, 4), 256, 0, stream>>>(
                xhwc, dfwd, dbwd, hold, Br, b_r, rhbf);
            gru_cand_mfma<<<dim3(200, 4), 256, 0, stream>>>(
                xhwc, dfwd, dbwd, hold, rhbf, Bu, Bo, b_u, b_o, hnew, out);
        }
    }
}

// Round 5
// 2016.738 us; speedup vs baseline: 6.3937x; 4.6722x over previous
//
#include <hip/hip_runtime.h>
#include <hip/hip_bf16.h>
#include <stdint.h>

#define EPS_GN 1e-5f
#define NEG_SLOPE 0.2f

static constexpr int  Bn   = 2;
static constexpr int  Cn   = 32;
static constexpr int  Dn   = 24;
static constexpr int  Hn   = 160;
static constexpr int  Wn   = 160;
static constexpr int  HWn  = Hn * Wn;              // 25600
static constexpr long DHWn = (long)Dn * HWn;       // 614400
static constexpr long NPIX = (long)Bn * Dn * HWn;  // 1228800

using frag8  = __attribute__((ext_vector_type(8)))  short;  // 8 bf16 (4 VGPRs)
using accf16 = __attribute__((ext_vector_type(16))) float;  // 32x32 C/D frag

__device__ __forceinline__ float bf2f(__hip_bfloat16 v) { return __bfloat162float(v); }
__device__ __forceinline__ __hip_bfloat16 f2bf(float v) { return __float2bfloat16(v); }
__device__ __forceinline__ float sigm(float v) { return 1.f / (1.f + __expf(-v)); }
__device__ __forceinline__ float tanh_(float v) {
    float e = __expf(2.f * v);
    return 1.f - 2.f / (e + 1.f);
}

// ---------------------------------------------------------------------------
// Pack conv1 weight w_f1 [64][32][3] into MFMA B-frag order.
// ---------------------------------------------------------------------------
__global__ __launch_bounds__(256) void bpack1_kernel(
    const float* __restrict__ w, __hip_bfloat16* __restrict__ dst)
{
    int t = blockIdx.x * 256 + threadIdx.x;
    if (t >= 6 * 2 * 64 * 8) return;
    int j    = t & 7;
    int lane = (t >> 3) & 63;
    int idx  = t >> 9;           // kb*2+nt
    int nt   = idx & 1;
    int kb   = idx >> 1;         // 0..5
    int o    = nt * 32 + (lane & 31);
    int k    = kb * 16 + (lane >> 5) * 8 + j;
    int ci   = k & 31;
    int kd   = k >> 5;
    dst[t] = f2bf(w[(o * 32 + ci) * 3 + kd]);
}

// ---------------------------------------------------------------------------
// Pack conv2 weight w_f2 [32][64][3]. K-order: k = kd*64 + ci.
// ---------------------------------------------------------------------------
__global__ __launch_bounds__(256) void bpack2_kernel(
    const float* __restrict__ w, __hip_bfloat16* __restrict__ dst)
{
    int t = blockIdx.x * 256 + threadIdx.x;
    if (t >= 12 * 64 * 8) return;
    int j    = t & 7;
    int lane = (t >> 3) & 63;
    int kb   = t >> 9;           // 0..11
    int o    = lane & 31;
    int k    = kb * 16 + (lane >> 5) * 8 + j;
    int ci   = k & 63;
    int kd   = k >> 6;
    dst[t] = f2bf(w[(o * 64 + ci) * 3 + kd]);
}

// ---------------------------------------------------------------------------
// Pack GRU conv weight [32][64][3][3] fp32 into MFMA B-fragment lane order.
// ---------------------------------------------------------------------------
__global__ __launch_bounds__(256) void bpack_kernel(
    const float* __restrict__ w, __hip_bfloat16* __restrict__ dst)
{
    int t = blockIdx.x * 256 + threadIdx.x;
    if (t >= 9 * 4 * 64 * 8) return;
    int j    = t & 7;
    int lane = (t >> 3) & 63;
    int kb   = (t >> 9) & 3;
    int tap  = t >> 11;
    int ci   = kb * 16 + (lane >> 5) * 8 + j;
    int o    = lane & 31;
    dst[t] = f2bf(w[(o * 64 + ci) * 9 + tap]);
}

// ---------------------------------------------------------------------------
// x [B][C][D][HW] fp32 -> xhwc [B][D][HW][32] bf16 via LDS transpose tile.
// ---------------------------------------------------------------------------
__global__ __launch_bounds__(256) void tohwc_kernel(
    const float* __restrict__ x, __hip_bfloat16* __restrict__ xhwc)
{
    __shared__ float tile[32][65];
    int bd = blockIdx.y;            // b*Dn+d
    int b  = bd / Dn, d = bd % Dn;
    int p0 = blockIdx.x * 64;
    const float* xb = x + (long)b * Cn * DHWn + (long)d * HWn + p0;
    for (int e = threadIdx.x; e < 2048; e += 256) {
        int c = e >> 6, p = e & 63;
        tile[c][p] = xb[(long)c * DHWn + p];
    }
    __syncthreads();
    __hip_bfloat16* ob = xhwc + ((long)bd * HWn + p0) * 32;
    for (int e = threadIdx.x; e < 2048; e += 256) {
        int p = e >> 5, c = e & 31;
        ob[p * 32 + c] = f2bf(tile[c][p]);
    }
}

// ---------------------------------------------------------------------------
// conv1 via MFMA: M=pixels (32/tile), N=64, K=96. GN stats fused.
// XCD-chunked block swizzle (2400 = 8 x 300) for d-slice L2 locality.
// ---------------------------------------------------------------------------
__global__ __launch_bounds__(256) void conv1_mfma(
    const __hip_bfloat16* __restrict__ xhwc,
    const __hip_bfloat16* __restrict__ Bp1,
    const float* __restrict__ b1,
    int b,
    __hip_bfloat16* __restrict__ A,
    float* __restrict__ gsum, float* __restrict__ gsq)
{
    int wave = threadIdx.x >> 6;
    int lane = threadIdx.x & 63;
    int ml   = lane & 31;
    int kh   = lane >> 5;
    int bid  = blockIdx.x;
    int sw   = (bid & 7) * 300 + (bid >> 3);
    int tile0 = sw * 8 + wave * 2;   // even; 800 tiles per d-slice

    frag8 bf[6][2];
#pragma unroll
    for (int kb = 0; kb < 6; kb++)
#pragma unroll
        for (int nt = 0; nt < 2; nt++)
            bf[kb][nt] = *(const frag8*)(Bp1 + ((kb * 2 + nt) * 64 + lane) * 8);

    int d  = tile0 / 800;
    int p0 = (tile0 % 800) * 32;

    accf16 acc[2][2];
#pragma unroll
    for (int t = 0; t < 2; t++)
#pragma unroll
        for (int nt = 0; nt < 2; nt++)
#pragma unroll
            for (int i = 0; i < 16; i++) acc[t][nt][i] = 0.f;

    for (int kd = 0; kd < 3; kd++) {
        int dd = d + kd - 1;
        bool valid = (unsigned)dd < (unsigned)Dn;
        const __hip_bfloat16* rp = xhwc + ((long)(b * Dn + dd) * HWn) * 32;
#pragma unroll
        for (int h2 = 0; h2 < 2; h2++) {
            int kb = kd * 2 + h2;
#pragma unroll
            for (int t = 0; t < 2; t++) {
                frag8 a = {};
                if (valid)
                    a = *(const frag8*)(rp + (long)(p0 + t * 32 + ml) * 32 + h2 * 16 + kh * 8);
                acc[t][0] = __builtin_amdgcn_mfma_f32_32x32x16_bf16(a, bf[kb][0], acc[t][0], 0, 0, 0);
                acc[t][1] = __builtin_amdgcn_mfma_f32_32x32x16_bf16(a, bf[kb][1], acc[t][1], 0, 0, 0);
            }
        }
    }

    float bias[2] = { b1[ml], b1[32 + ml] };
    float s[2] = {0.f, 0.f}, q[2] = {0.f, 0.f};
    __hip_bfloat16* Ap = A + (long)d * HWn * 64;
#pragma unroll
    for (int t = 0; t < 2; t++) {
        int pb = p0 + t * 32;
#pragma unroll
        for (int nt = 0; nt < 2; nt++) {
#pragma unroll
            for (int i = 0; i < 16; i++) {
                int row = (i & 3) + 8 * (i >> 2) + 4 * kh;
                float v = acc[t][nt][i] + bias[nt];
                Ap[(long)(pb + row) * 64 + nt * 32 + ml] = f2bf(v);
                s[nt] += v;
                q[nt] += v * v;
            }
        }
    }
#pragma unroll
    for (int nt = 0; nt < 2; nt++) {
        s[nt] += __shfl_xor(s[nt], 32);
        q[nt] += __shfl_xor(q[nt], 32);
    }
    __shared__ float ss[64], sq[64];
    if (threadIdx.x < 64) { ss[threadIdx.x] = 0.f; sq[threadIdx.x] = 0.f; }
    __syncthreads();
    if (lane < 32) {
        atomicAdd(&ss[ml],      s[0]); atomicAdd(&sq[ml],      q[0]);
        atomicAdd(&ss[32 + ml], s[1]); atomicAdd(&sq[32 + ml], q[1]);
    }
    __syncthreads();
    if (threadIdx.x < 64) {
        atomicAdd(&gsum[b * 64 + threadIdx.x], ss[threadIdx.x]);
        atomicAdd(&gsq [b * 64 + threadIdx.x], sq[threadIdx.x]);
    }
}

__global__ __launch_bounds__(64) void finalize_kernel(
    const float* __restrict__ gsum, const float* __restrict__ gsq,
    const float* __restrict__ gn_g, const float* __restrict__ gn_b,
    float* __restrict__ scal, float* __restrict__ shft, int b)
{
    int ci = threadIdx.x;
    if (ci >= 64) return;
    int g = ci >> 3;
    float s = 0.f, qq = 0.f;
#pragma unroll
    for (int k = 0; k < 8; k++) {
        s  += gsum[b * 64 + g * 8 + k];
        qq += gsq [b * 64 + g * 8 + k];
    }
    float N   = 8.0f * (float)DHWn;
    float mu  = s / N;
    float var = qq / N - mu * mu;
    float rs  = rsqrtf(var + EPS_GN);
    float scv = rs * gn_g[ci];
    scal[b * 64 + ci] = scv;
    shft[b * 64 + ci] = gn_b[ci] - mu * scv;
}

// ---------------------------------------------------------------------------
// In-place GN affine + LeakyReLU on A [D][HW][64] bf16 (one batch).
// ---------------------------------------------------------------------------
__global__ __launch_bounds__(256) void act_kernel(
    __hip_bfloat16* __restrict__ A,
    const float* __restrict__ scal, const float* __restrict__ shft, int b)
{
    __shared__ float sc[64], sh[64];
    if (threadIdx.x < 64) {
        sc[threadIdx.x] = scal[b * 64 + threadIdx.x];
        sh[threadIdx.x] = shft[b * 64 + threadIdx.x];
    }
    __syncthreads();
    long i0 = ((long)blockIdx.x * 256 + threadIdx.x) * 8;
    __hip_bfloat16 loc[8];
    *(frag8*)loc = *(const frag8*)(A + i0);
    int c0 = (int)(i0 & 63);
#pragma unroll
    for (int j = 0; j < 8; j++) {
        float f  = bf2f(loc[j]);
        float an = fmaf(f, sc[c0 + j], sh[c0 + j]);
        loc[j]   = f2bf(fmaxf(an, NEG_SLOPE * an));
    }
    *(frag8*)(A + i0) = *(frag8*)loc;
}

// ---------------------------------------------------------------------------
// conv2 via MFMA: M=pixels, N=32, K=192. XCD-chunked swizzle (4800 = 8x600).
// Residual add + coalesced store via padded LDS transpose.
// ---------------------------------------------------------------------------
__global__ __launch_bounds__(256) void conv2_mfma(
    const __hip_bfloat16* __restrict__ Aact,
    const __hip_bfloat16* __restrict__ Bp2,
    const float* __restrict__ b2,
    const float* __restrict__ x,
    float* __restrict__ out,
    int b)
{
    int wave = threadIdx.x >> 6;
    int lane = threadIdx.x & 63;
    int ml   = lane & 31;
    int kh   = lane >> 5;
    int bid  = blockIdx.x;
    int sw   = (bid & 7) * 600 + (bid >> 3);
    int tile = sw * 4 + wave;   // 0..19199

    frag8 bf[12];
#pragma unroll
    for (int kb = 0; kb < 12; kb++)
        bf[kb] = *(const frag8*)(Bp2 + (kb * 64 + lane) * 8);

    int d  = tile / 800;
    int p0 = (tile % 800) * 32;

    accf16 acc;
#pragma unroll
    for (int i = 0; i < 16; i++) acc[i] = 0.f;

    for (int kd = 0; kd < 3; kd++) {
        int dd = d + kd - 1;
        bool valid = (unsigned)dd < (unsigned)Dn;
        const __hip_bfloat16* rp = Aact + (long)dd * HWn * 64;
#pragma unroll
        for (int qq = 0; qq < 4; qq++) {
            frag8 a = {};
            if (valid)
                a = *(const frag8*)(rp + (long)(p0 + ml) * 64 + qq * 16 + kh * 8);
            acc = __builtin_amdgcn_mfma_f32_32x32x16_bf16(a, bf[kd * 4 + qq], acc, 0, 0, 0);
        }
    }

    __shared__ float tb[4][32][33];
    float bias = b2[ml];
    const float* xb = x   + (long)b * Cn * DHWn + (long)d * HWn;
    float*       ob = out + (long)b * Cn * DHWn + (long)d * HWn;
#pragma unroll
    for (int i = 0; i < 16; i++) {
        int row = (i & 3) + 8 * (i >> 2) + 4 * kh;
        tb[wave][row][ml] = acc[i] + bias;
    }
    // wave-private tile: same-wave DS ordering + compiler lgkmcnt waits
#pragma unroll
    for (int r2 = 0; r2 < 16; r2++) {
        int c = r2 * 2 + kh;
        float v = tb[wave][ml][c] + xb[(long)c * DHWn + p0 + ml];
        ob[(long)c * DHWn + p0 + ml] = v;
    }
}

// ---------------------------------------------------------------------------
// GRU full step, ONE kernel per d-step (24 dispatches total).
// Wave owns a 4x8 pixel patch. Phase 1: compute r over the 6x10 halo patch
// (2 masked M-tiles) and store r*h into wave-private LDS ([64][40] bf16,
// pad 40 => 16B-aligned b128 reads, OOB halo pixels store 0).
// Phase 2: u = sigm(conv([x,h])), cand = tanh(conv([x, rh_LDS])),
// h_new = (1-u)h + u*cand -> hnew (dbuf) ; out += h_new via LDS transpose.
// No barriers (all LDS wave-private). XCD swizzle: 200 blocks = 8 x 25.
// ---------------------------------------------------------------------------
__global__ __launch_bounds__(256) void gru_step_mfma(
    const __hip_bfloat16* __restrict__ xhwc,  // [B][D][HW][32]
    int dfwd, int dbwd,
    const __hip_bfloat16* __restrict__ hold,  // [2][B][HW][32]
    const __hip_bfloat16* __restrict__ Bu,
    const __hip_bfloat16* __restrict__ Br,
    const __hip_bfloat16* __restrict__ Bo,
    const float* __restrict__ bu, const float* __restrict__ br,
    const float* __restrict__ bo,
    __hip_bfloat16* __restrict__ hnew,
    float* __restrict__ out)
{
    int db   = blockIdx.y;          // dir*2 + b
    int dir  = db >> 1, b = db & 1;
    int d    = dir ? dbwd : dfwd;
    int wave = threadIdx.x >> 6;
    int lane = threadIdx.x & 63;
    int ml   = lane & 31;
    int kh   = lane >> 5;

    int bidx = blockIdx.x;
    int sw   = (bidx & 7) * 25 + (bidx >> 3);   // 200 = 8 x 25, bijective
    int tile = sw * 4 + wave;                   // 0..799
    int trow = tile / 20, tcol = tile % 20;     // 40 x 20 patches of 4x8
    int py0  = trow * 4,  px0  = tcol * 8;

    __shared__ __hip_bfloat16 rhl[4][64][40];   // wave-private rh halo patch
    __shared__ float tb[4][32][33];             // wave-private out transpose

    const __hip_bfloat16* xb  = xhwc + ((long)b * Dn + d) * HWn * 32;
    const __hip_bfloat16* hb  = hold + (long)db * HWn * 32;
    __hip_bfloat16*       hnb = hnew + (long)db * HWn * 32;

    float bias_r = br[ml], bias_u = bu[ml], bias_o = bo[ml];

    // ---------------- phase 1: r over halo patch (60 px in 2 M-tiles) ------
    {
        // lane's halo pixel for each tile: hp = t*32 + ml
        int hr0 = ml / 10,        hc0 = ml - hr0 * 10;
        int hp1 = 32 + ml;
        int hr1 = hp1 / 10,       hc1 = hp1 - hr1 * 10;
        int hy[2] = { py0 - 1 + hr0, py0 - 1 + hr1 };
        int hx[2] = { px0 - 1 + hc0, px0 - 1 + hc1 };

        accf16 ar[2];
#pragma unroll
        for (int t = 0; t < 2; t++)
#pragma unroll
            for (int i = 0; i < 16; i++) ar[t][i] = 0.f;

        for (int tap = 0; tap < 9; tap++) {
            int dy = tap / 3 - 1, dx = tap % 3 - 1;
            bool ok[2]; long poff[2];
#pragma unroll
            for (int t = 0; t < 2; t++) {
                int yy = hy[t] + dy, xx = hx[t] + dx;
                ok[t]   = ((unsigned)yy < (unsigned)Hn) & ((unsigned)xx < (unsigned)Wn);
                poff[t] = ((long)(yy * Wn + xx)) * 32;
            }
#pragma unroll
            for (int kb = 0; kb < 4; kb++) {
                frag8 brf = *(const frag8*)(Br + ((tap * 4 + kb) * 64 + lane) * 8);
                int ch = kb * 16 + kh * 8;
                const __hip_bfloat16* bsel = (kb < 2) ? (xb + ch) : (hb + (ch - 32));
#pragma unroll
                for (int t = 0; t < 2; t++) {
                    frag8 a = {};
                    if (ok[t]) a = *(const frag8*)(bsel + poff[t]);
                    ar[t] = __builtin_amdgcn_mfma_f32_32x32x16_bf16(a, brf, ar[t], 0, 0, 0);
                }
            }
        }
        // epilogue: rh = sigm(r)*h into LDS; OOB pixels -> 0
#pragma unroll
        for (int t = 0; t < 2; t++) {
#pragma unroll
            for (int i = 0; i < 16; i++) {
                int row = (i & 3) + 8 * (i >> 2) + 4 * kh;
                int hp2 = t * 32 + row;                  // 0..63 (60..63 pad)
                int hr  = hp2 / 10, hc = hp2 - hr * 10;
                int hy2 = py0 - 1 + hr, hx2 = px0 - 1 + hc;
                bool v  = ((unsigned)hy2 < (unsigned)Hn) & ((unsigned)hx2 < (unsigned)Wn);
                float hpv = v ? bf2f(hb[((long)(hy2 * Wn + hx2)) * 32 + ml]) : 0.f;
                rhl[wave][hp2][ml] = f2bf(sigm(ar[t][i] + bias_r) * hpv);
            }
        }
    }
    // no __syncthreads: rhl is wave-private; compiler orders same-wave ds ops

    // ---------------- phase 2: u + cand + h update + out ---------------------
    {
        int prow = ml >> 3, pcol = ml & 7;
        int oy = py0 + prow, ox = px0 + pcol;

        accf16 au, ao;
#pragma unroll
        for (int i = 0; i < 16; i++) { au[i] = 0.f; ao[i] = 0.f; }

        for (int tap = 0; tap < 9; tap++) {
            int dy = tap / 3 - 1, dx = tap % 3 - 1;
            int yy = oy + dy, xx = ox + dx;
            bool ok  = ((unsigned)yy < (unsigned)Hn) & ((unsigned)xx < (unsigned)Wn);
            long poff = ((long)(yy * Wn + xx)) * 32;
            int hp = (prow + 1 + dy) * 10 + (pcol + 1 + dx);   // 0..59, in-bounds
#pragma unroll
            for (int kb = 0; kb < 4; kb++) {
                frag8 buf = *(const frag8*)(Bu + ((tap * 4 + kb) * 64 + lane) * 8);
                frag8 bof = *(const frag8*)(Bo + ((tap * 4 + kb) * 64 + lane) * 8);
                int ch = kb * 16 + kh * 8;
                if (kb < 2) {
                    frag8 a = {};
                    if (ok) a = *(const frag8*)(xb + ch + poff);
                    au = __builtin_amdgcn_mfma_f32_32x32x16_bf16(a, buf, au, 0, 0, 0);
                    ao = __builtin_amdgcn_mfma_f32_32x32x16_bf16(a, bof, ao, 0, 0, 0);
                } else {
                    frag8 ah = {};
                    if (ok) ah = *(const frag8*)(hb + (ch - 32) + poff);
                    au = __builtin_amdgcn_mfma_f32_32x32x16_bf16(ah, buf, au, 0, 0, 0);
                    frag8 arh = *(const frag8*)(&rhl[wave][hp][(kb - 2) * 16 + kh * 8]);
                    ao = __builtin_amdgcn_mfma_f32_32x32x16_bf16(arh, bof, ao, 0, 0, 0);
                }
            }
        }

        float* ob = out + (long)b * Cn * DHWn + (long)d * HWn;
#pragma unroll
        for (int i = 0; i < 16; i++) {
            int lp  = (i & 3) + 8 * (i >> 2) + 4 * kh;    // own pixel 0..31
            int pyy = py0 + (lp >> 3), pxx = px0 + (lp & 7);
            long pix = (long)pyy * Wn + pxx;
            float uu  = sigm(au[i] + bias_u);
            float cc  = tanh_(ao[i] + bias_o);
            float hpv = bf2f(hb[pix * 32 + ml]);
            float hn  = (1.f - uu) * hpv + uu * cc;
            hnb[pix * 32 + ml] = f2bf(hn);
            tb[wave][lp][ml] = hn;
        }
        int pyy = py0 + (ml >> 3), pxx = px0 + (ml & 7);
        long pix = (long)pyy * Wn + pxx;
#pragma unroll
        for (int r2 = 0; r2 < 16; r2++) {
            int c = r2 * 2 + kh;
            ob[(long)c * DHWn + pix] += tb[wave][ml][c];
        }
    }
}

// ---------------------------------------------------------------------------
extern "C" void kernel_launch(void* const* d_in, const int* in_sizes, int n_in,
                              void* d_out, int out_size, void* d_ws, size_t ws_size,
                              hipStream_t stream)
{
    const float* x    = (const float*)d_in[0];
    const float* w_f1 = (const float*)d_in[1];
    const float* b_f1 = (const float*)d_in[2];
    const float* gn_g = (const float*)d_in[3];
    const float* gn_b = (const float*)d_in[4];
    const float* w_f2 = (const float*)d_in[5];
    const float* b_f2 = (const float*)d_in[6];
    const float* w_u  = (const float*)d_in[7];
    const float* b_u  = (const float*)d_in[8];
    const float* w_r  = (const float*)d_in[9];
    const float* b_r  = (const float*)d_in[10];
    const float* w_o  = (const float*)d_in[11];
    const float* b_o  = (const float*)d_in[12];
    float* out = (float*)d_out;

    // ---- workspace layout ----
    char* ws = (char*)d_ws;
    __hip_bfloat16* Bp1 = (__hip_bfloat16*)ws;            // 6144 elems
    __hip_bfloat16* Bp2 = Bp1 + 6144;                     // 6144
    __hip_bfloat16* Bu  = Bp2 + 6144;                     // 18432 each
    __hip_bfloat16* Br  = Bu + 18432;
    __hip_bfloat16* Bo  = Br + 18432;
    float* gsum = (float*)(Bo + 18432);                   // 128
    float* gsq  = gsum + 128;                             // 128
    float* scal = gsq + 128;                              // 128
    float* shft = scal + 128;                             // 128
    char* big = (char*)(shft + 128);
    big = (char*)(((uintptr_t)big + 255) & ~(uintptr_t)255);

    __hip_bfloat16* xhwc = (__hip_bfloat16*)big;                  // 78,643,200 B
    __hip_bfloat16* Apre = (__hip_bfloat16*)(big + 78643200L);    // 78,643,200 B
    __hip_bfloat16* hA   = (__hip_bfloat16*)(big + 78643200L);    //  6,553,600 B
    __hip_bfloat16* hB   = (__hip_bfloat16*)(big + 85196800L);    //  6,553,600 B

    size_t need = (size_t)(big - ws) + 157286400UL;
    if (ws_size < need) return;  // workspace too small

    // ---- weight transforms ----
    bpack1_kernel<<<24, 256, 0, stream>>>(w_f1, Bp1);
    bpack2_kernel<<<24, 256, 0, stream>>>(w_f2, Bp2);
    bpack_kernel<<<72, 256, 0, stream>>>(w_u, Bu);
    bpack_kernel<<<72, 256, 0, stream>>>(w_r, Br);
    bpack_kernel<<<72, 256, 0, stream>>>(w_o, Bo);
    hipMemsetAsync(gsum, 0, 256 * sizeof(float), stream);  // gsum+gsq

    // ---- HWC transpose (feeds conv1 AND the GRU phase) ----
    tohwc_kernel<<<dim3(400, Bn * Dn), 256, 0, stream>>>(x, xhwc);

    // ---- slice_flow path via MFMA, one batch at a time (Apre reused) ----
    for (int b = 0; b < Bn; b++) {
        conv1_mfma<<<2400, 256, 0, stream>>>(xhwc, Bp1, b_f1, b, Apre, gsum, gsq);
        finalize_kernel<<<1, 64, 0, stream>>>(gsum, gsq, gn_g, gn_b, scal, shft, b);
        act_kernel<<<19200, 256, 0, stream>>>(Apre, scal, shft, b);
        conv2_mfma<<<4800, 256, 0, stream>>>(Apre, Bp2, b_f2, x, out, b);
    }

    // ---- GRU phase: 24 fused step dispatches, double-buffered h ----
    hipMemsetAsync(hA, 0, 6553600, stream);
    __hip_bfloat16* hbufs[2] = { hA, hB };
    for (int s = 0; s < Dn; s++) {
        int dfwd = s, dbwd = Dn - 1 - s;
        __hip_bfloat16* hold = hbufs[s & 1];
        __hip_bfloat16* hnew = hbufs[(s + 1) & 1];
        gru_step_mfma<<<dim3(200, 4), 256, 0, stream>>>(
            xhwc, dfwd, dbwd, hold, Bu, Br, Bo, b_u, b_r, b_o, hnew, out);
    }
}